// Round 5
// baseline (128.240 us; speedup 1.0000x reference)
//
#include <hip/hip_runtime.h>
#include <hip/hip_fp16.h>

#define HH 96
#define WW 96
#define CC 128

typedef float f32x4 __attribute__((ext_vector_type(4)));
typedef short short8 __attribute__((ext_vector_type(8)));
typedef _Float16 f16x8 __attribute__((ext_vector_type(8)));

union U32H2 { unsigned int u; __half2 h; };
__device__ __forceinline__ unsigned int pack2(float x, float y){ U32H2 t; t.h=__floats2half2_rn(x,y); return t.u; }

// f32 -> bf16 round-to-nearest-even
__device__ __forceinline__ unsigned short f2bf(float x){
  unsigned int u = __float_as_uint(x);
  return (unsigned short)((u + 0x7FFFu + ((u >> 16) & 1u)) >> 16);
}
__device__ __forceinline__ unsigned int pkbf(float a, float b){
  return (unsigned)f2bf(a) | ((unsigned)f2bf(b) << 16);
}

union U4S8 { uint4 q; short8 s; };
union U4H8 { uint4 q; f16x8 h; };

// -------------------------------------------------------------------------
// Kernel 1 (MFMA): cost volume via banded GEMM.
// Per (y, dy): C[16px, 24win] = prv[y,16px,128c] x nxt[y+dy-4, win, 128c]^T
// Round-5 changes vs round-4 (target: 2 blocks/CU co-residency):
//  - prv A-fragments staged through LDS (ptile) instead of per-wave global
//    loads -> VGPR <= 56; with acc 72 AGPR total <= 128 regs/lane.
//  - __launch_bounds__(512, 4): 4 waves/SIMD -> 2 x 8-wave blocks per CU;
//    inter-block phase interleave hides stage latency.
//  - ntile win-stride 32 -> 24 (+16-slot overrun pad). Overrun reads feed
//    only od>8 band positions that are never extracted (C columns are
//    independent), so garbage there is harmless. LDS 65 KB -> 2 blocks fit.
// -------------------------------------------------------------------------
__global__ __launch_bounds__(512, 4) void k_cost_mfma(const float* __restrict__ prv,
                                                      const float* __restrict__ nxt,
                                                      __half* __restrict__ cost) {
  const int x0 = blockIdx.x * 16;
  const int y0 = blockIdx.y * 8;
  const int b  = blockIdx.z;
  const int tid = threadIdx.x;
  const int w = tid >> 6, l = tid & 63;
  const int lm = l & 15, lq = l >> 4;
  const int y = y0 + w;

  __shared__ uint4 ntile[2][1568];   // [buf][(r*4+kq)*24 + p], p<24, +16 pad
  __shared__ uint4 ptile[2][512];    // [buf][(row*4+q)*16 + px]

  f32x4 acc[9][2];
#pragma unroll
  for (int dy = 0; dy < 9; ++dy) {
    acc[dy][0] = (f32x4){0.f,0.f,0.f,0.f};
    acc[dy][1] = (f32x4){0.f,0.f,0.f,0.f};
  }

  // staging coordinates (hoisted)
  const int sr = tid >> 5, sp = tid & 31;          // nxt: 16 rows x 32 (24 used)
  const int gr = y0 - 4 + sr, gc = x0 - 4 + sp;
  const bool nok = (sp < 24) && ((unsigned)gr < HH) && ((unsigned)gc < WW);
  const float* nrow = &nxt[((size_t)(b*HH + gr)*WW + gc)*CC];
  const int sq = (tid >> 4) & 3, spp = tid & 15;   // prv: row=tid>>6, q, px
  const float* prow = &prv[((size_t)(b*HH + y0 + (tid >> 6))*WW + x0 + spp)*CC + sq*8];

  auto stage = [&](int ks, int buf){
    float4 f[8];
#pragma unroll
    for (int j = 0; j < 8; ++j) f[j] = make_float4(0.f,0.f,0.f,0.f);
    if (nok) {
      const float* src = nrow + ks*32;
#pragma unroll
      for (int j = 0; j < 8; ++j) f[j] = *(const float4*)(src + j*4);
    }
    const float4 g0 = *(const float4*)(prow + ks*32);
    const float4 g1 = *(const float4*)(prow + ks*32 + 4);
    if (sp < 24) {
#pragma unroll
      for (int kq = 0; kq < 4; ++kq) {
        uint4 d;
        d.x = pkbf(f[2*kq].x,   f[2*kq].y);
        d.y = pkbf(f[2*kq].z,   f[2*kq].w);
        d.z = pkbf(f[2*kq+1].x, f[2*kq+1].y);
        d.w = pkbf(f[2*kq+1].z, f[2*kq+1].w);
        ntile[buf][(sr*4 + kq)*24 + sp] = d;
      }
    }
    uint4 pd;
    pd.x = pkbf(g0.x, g0.y); pd.y = pkbf(g0.z, g0.w);
    pd.z = pkbf(g1.x, g1.y); pd.w = pkbf(g1.z, g1.w);
    ptile[buf][tid] = pd;     // slot (row*4+q)*16+px == tid -> conflict-free
  };

  stage(0, 0);

#pragma unroll 1
  for (int ks = 0; ks < 4; ++ks) {
    __syncthreads();                    // buf[ks&1] ready; buf^1 free
    if (ks < 3) stage(ks + 1, (ks + 1) & 1);

    const int cur = ks & 1;
    U4S8 af;
    af.q = ptile[cur][(w*4 + lq)*16 + lm];   // A[m=lm][k=lq*8+j]
#pragma unroll
    for (int dy = 0; dy < 9; ++dy) {
      const int sb = ((w + dy)*4 + lq)*24;
      U4S8 b0, b1;
      b0.q = ntile[cur][sb + lm];
      b1.q = ntile[cur][sb + 16 + lm];
      acc[dy][0] = __builtin_amdgcn_mfma_f32_16x16x32_bf16(af.s, b0.s, acc[dy][0], 0, 0, 0);
      acc[dy][1] = __builtin_amdgcn_mfma_f32_16x16x32_bf16(af.s, b1.s, acc[dy][1], 0, 0, 0);
    }
  }

  // band extraction: lane holds C[m = lq*4+reg][p = t*16+lm]; od = p - m
#pragma unroll
  for (int t = 0; t < 2; ++t) {
#pragma unroll
    for (int reg = 0; reg < 4; ++reg) {
      const int m  = lq*4 + reg;
      const int od = t*16 + lm - m;
      if (od >= 0 && od <= 8) {
        __half* bp = &cost[((size_t)(b*HH + y)*WW + x0 + m)*96 + od];
#pragma unroll
        for (int dy = 0; dy < 9; ++dy) {
          float v = acc[dy][t][reg] * 0.0078125f;
          v = (v >= 0.f) ? v : 0.1f * v;
          bp[dy*9] = __float2half(v);
        }
      }
    }
  }
}

// -------------------------------------------------------------------------
// Kernel 2 (MFMA): conv as GEMM + gather.  (unchanged from round 4)
// G[px, j=tap*2+n] = sum_k feat[px,k] * W[tap,k,n]   (M=324, K=352, N=18->32)
// out[y,x,n] = cb[n] + sum_tap G[y+dy-1, x+dx-1, tap*2+n]
// -------------------------------------------------------------------------
__global__ __launch_bounds__(512) void k_conv_gemm(const float* __restrict__ prv,
                                                   const float* __restrict__ nxt,
                                                   const __half* __restrict__ cost,
                                                   const float* __restrict__ cw,
                                                   const float* __restrict__ cb,
                                                   float* __restrict__ out) {
  const int tw0 = blockIdx.x*16, th0 = blockIdx.y*16, b = blockIdx.z;
  const int tid = threadIdx.x;
  const int w = tid >> 6, l = tid & 63;
  const int lm = l & 15, lq = l >> 4;

  __shared__ __align__(16) char smem[49408];
  uint4*        feat16 = (uint4*)smem;               // [336 px][40 half]
  float*        Gf     = (float*)smem;               // [324][20] f32 (aliased)
  float2*       Gf2    = (float2*)smem;
  uint4*        B2     = (uint4*)(smem + 26880);     // [(kc*4+lq)*32 + j]
  __half*       B2h    = (__half*)(smem + 26880);

#pragma unroll 1
  for (int i = tid; i < 5632; i += 512) ((unsigned int*)B2)[i] = 0u;
#pragma unroll 1
  for (int i = tid; i < 240; i += 512) ((unsigned int*)smem)[6480 + i] = 0u;
#pragma unroll 1
  for (int i = tid; i < 352*18; i += 512) {
    const int ci = i / 18, j = i - 18*ci;
    if (ci >= 81 && ci < 96) continue;
    const int wci = (ci < 81) ? ci : ci - 15;
    const int tap = j >> 1, n = j & 1;
    const float v = cw[(tap*337 + wci)*2 + n];
    const int kk = ci & 31;
    B2h[((((ci >> 5)*4 + (kk >> 3))*32) + j)*8 + (kk & 7)] = __float2half(v);
  }

  f32x4 acc[3][2];
#pragma unroll
  for (int i = 0; i < 3; ++i) { acc[i][0] = (f32x4){0,0,0,0}; acc[i][1] = (f32x4){0,0,0,0}; }

#pragma unroll 1
  for (int kc = 0; kc < 11; ++kc) {
    __syncthreads();
#pragma unroll 1
    for (int i = tid; i < 648; i += 512) {
      const int px = i >> 1, half = i & 1;
      const int hr = px / 18, hc = px - 18*hr;
      const int gr = th0 - 1 + hr, gc = tw0 - 1 + hc;
      uint4 d0 = make_uint4(0,0,0,0), d1 = make_uint4(0,0,0,0);
      if ((unsigned)gr < HH && (unsigned)gc < WW) {
        const size_t pixi = (size_t)(b*HH + gr)*WW + gc;
        if (kc < 3) {
          const uint4* cs = (const uint4*)&cost[pixi*96 + kc*32 + half*16];
          d0 = cs[0]; d1 = cs[1];
        } else {
          const float* src = (kc < 7) ? prv : nxt;
          const int c0 = ((kc < 7) ? (kc-3) : (kc-7))*32 + half*16;
          const float4 f0 = *(const float4*)&src[pixi*128 + c0];
          const float4 f1 = *(const float4*)&src[pixi*128 + c0 + 4];
          const float4 f2 = *(const float4*)&src[pixi*128 + c0 + 8];
          const float4 f3 = *(const float4*)&src[pixi*128 + c0 + 12];
          d0 = make_uint4(pack2(f0.x,f0.y), pack2(f0.z,f0.w), pack2(f1.x,f1.y), pack2(f1.z,f1.w));
          d1 = make_uint4(pack2(f2.x,f2.y), pack2(f2.z,f2.w), pack2(f3.x,f3.y), pack2(f3.z,f3.w));
        }
      }
      feat16[5*px + 2*half]     = d0;
      feat16[5*px + 2*half + 1] = d1;
    }
    __syncthreads();

    U4H8 bf0, bf1;
    bf0.q = B2[(kc*4 + lq)*32 + lm];
    bf1.q = B2[(kc*4 + lq)*32 + 16 + lm];
#pragma unroll
    for (int i = 0; i < 3; ++i) {
      const int mf = w + 8*i;
      if (mf < 21) {
        U4H8 af;
        af.q = feat16[5*(16*mf + lm) + lq];
        acc[i][0] = __builtin_amdgcn_mfma_f32_16x16x32_f16(af.h, bf0.h, acc[i][0], 0, 0, 0);
        acc[i][1] = __builtin_amdgcn_mfma_f32_16x16x32_f16(af.h, bf1.h, acc[i][1], 0, 0, 0);
      }
    }
  }
  __syncthreads();

#pragma unroll
  for (int i = 0; i < 3; ++i) {
    const int mf = w + 8*i;
    if (mf >= 21) continue;
#pragma unroll
    for (int r = 0; r < 4; ++r) {
      const int px = 16*mf + lq*4 + r;
      if (px < 324) {
        Gf[px*20 + lm] = acc[i][0][r];
        if (lm < 2) Gf[px*20 + 16 + lm] = acc[i][1][r];
      }
    }
  }
  __syncthreads();

  if (tid < 512) {
    const int px = tid >> 1, n = tid & 1;
    const int ty = px >> 4, tx = px & 15;
    float s = cb[n];
#pragma unroll
    for (int p = 0; p < 9; ++p) {
      const int dy = p / 3, dx = p - 3*dy;
      const int hp = (ty + dy)*18 + (tx + dx);
      const float2 g = Gf2[hp*10 + p];
      s += n ? g.y : g.x;
    }
    out[((size_t)(b*HH + th0 + ty)*WW + (tw0 + tx))*2 + n] = s;
  }
}

extern "C" void kernel_launch(void* const* d_in, const int* in_sizes, int n_in,
                              void* d_out, int out_size, void* d_ws, size_t ws_size,
                              hipStream_t stream) {
  const float* prv = (const float*)d_in[0];
  const float* nxt = (const float*)d_in[1];
  const float* cw  = (const float*)d_in[2];
  const float* cb  = (const float*)d_in[3];
  __half* cost = (__half*)d_ws;   // 16*96*96*96*2 = 28,311,552 bytes

  k_cost_mfma<<<dim3(6, 12, 16), dim3(512), 0, stream>>>(prv, nxt, cost);
  k_conv_gemm<<<dim3(6, 6, 16), dim3(512), 0, stream>>>(prv, nxt, cost, cw, cb, (float*)d_out);
}

// Round 6
// 118.519 us; speedup vs baseline: 1.0820x; 1.0820x over previous
//
#include <hip/hip_runtime.h>
#include <hip/hip_fp16.h>

#define HH 96
#define WW 96
#define CC 128

typedef float f32x4 __attribute__((ext_vector_type(4)));
typedef short short8 __attribute__((ext_vector_type(8)));
typedef _Float16 f16x8 __attribute__((ext_vector_type(8)));

union U32H2 { unsigned int u; __half2 h; };
__device__ __forceinline__ unsigned int pack2(float x, float y){ U32H2 t; t.h=__floats2half2_rn(x,y); return t.u; }

// f32 -> bf16 round-to-nearest-even
__device__ __forceinline__ unsigned short f2bf(float x){
  unsigned int u = __float_as_uint(x);
  return (unsigned short)((u + 0x7FFFu + ((u >> 16) & 1u)) >> 16);
}
__device__ __forceinline__ unsigned int pkbf(float a, float b){
  return (unsigned)f2bf(a) | ((unsigned)f2bf(b) << 16);
}

union U4S8 { uint4 q; short8 s; };
union U4H8 { uint4 q; f16x8 h; };

// MMA inner step for a dy-range (wave-uniform template)
template<int DY0, int NDY>
static __device__ __forceinline__ void cost_mma(const uint4* __restrict__ nt,
                                                int yr, int lq, int lm,
                                                short8 a, f32x4 (&acc)[5][2]) {
#pragma unroll
  for (int d = 0; d < NDY; ++d) {
    const int sb = ((yr + DY0 + d)*4 + lq)*24;
    U4S8 b0, b1;
    b0.q = nt[sb + lm];
    b1.q = nt[sb + 16 + lm];
    acc[d][0] = __builtin_amdgcn_mfma_f32_16x16x32_bf16(a, b0.s, acc[d][0], 0, 0, 0);
    acc[d][1] = __builtin_amdgcn_mfma_f32_16x16x32_bf16(a, b1.s, acc[d][1], 0, 0, 0);
  }
}

// -------------------------------------------------------------------------
// Kernel 1 (MFMA): cost volume via banded GEMM.
// Round-6 structure: block = 512 thr = 8 waves = 4 y-rows x 2 dy-halves
// (hf=0: dy 0..4, hf=1: dy 5..8).  acc = [5][2] f32x4 = 40 regs -> total
// ~100 unified regs/lane -> (512,4) holds WITHOUT spill (round-5 spilled:
// acc 72 + 64 VGPR = 136 > 128 cap -> 54 MB scratch writes).
// 2 x 8-wave blocks co-resident per CU -> inter-block phase overlap.
// LDS 48 KB: ntile 12 halo rows (stride 24 uint4, +pad for t=1 overrun;
// overrun feeds only od>8 never-extracted band slots), ptile 4 rows.
// -------------------------------------------------------------------------
__global__ __launch_bounds__(512, 4) void k_cost_mfma(const float* __restrict__ prv,
                                                      const float* __restrict__ nxt,
                                                      __half* __restrict__ cost) {
  const int x0 = blockIdx.x * 16;
  const int y0 = blockIdx.y * 4;       // 4 output rows per block
  const int b  = blockIdx.z;
  const int tid = threadIdx.x;
  const int w = tid >> 6, l = tid & 63;
  const int lm = l & 15, lq = l >> 4;
  const int yr = w >> 1, hf = w & 1;   // y-row 0..3, dy-half
  const int y = y0 + yr;

  __shared__ uint4 ntile[2][1280];     // [(r*4+kq)*24 + p], r 0..11, + pad
  __shared__ uint4 ptile[2][256];      // [(row*4+q)*16 + px]

  f32x4 acc[5][2];
#pragma unroll
  for (int d = 0; d < 5; ++d) {
    acc[d][0] = (f32x4){0.f,0.f,0.f,0.f};
    acc[d][1] = (f32x4){0.f,0.f,0.f,0.f};
  }

  // staging coordinates (hoisted):
  // threads 0..383: nxt 12 halo rows x 32 cols (24 used)
  const int sr = tid >> 5, sp = tid & 31;
  const int gr = y0 - 4 + sr, gc = x0 - 4 + sp;
  const bool nok = (tid < 384) && (sp < 24) && ((unsigned)gr < HH) && ((unsigned)gc < WW);
  const float* nrow = &nxt[((size_t)(b*HH + ((unsigned)gr < HH ? gr : 0))*WW
                            + ((unsigned)gc < WW ? gc : 0))*CC];
  // threads 384..511: prv 4 rows x 16 px, two kq quarters each
  const int pidx = (tid >= 384) ? (tid - 384) : 0;
  const int prow_i = pidx >> 5, pq0 = (pidx >> 4) & 1, ppx = pidx & 15;
  const float* prow = &prv[((size_t)(b*HH + y0 + prow_i)*WW + x0 + ppx)*CC];

  auto stage = [&](int ks, int buf){
    if (tid < 384) {
      float4 f[8];
#pragma unroll
      for (int j = 0; j < 8; ++j) f[j] = make_float4(0.f,0.f,0.f,0.f);
      if (nok) {
        const float* src = nrow + ks*32;
#pragma unroll
        for (int j = 0; j < 8; ++j) f[j] = *(const float4*)(src + j*4);
      }
      if (sp < 24) {
#pragma unroll
        for (int kq = 0; kq < 4; ++kq) {
          uint4 d;
          d.x = pkbf(f[2*kq].x,   f[2*kq].y);
          d.y = pkbf(f[2*kq].z,   f[2*kq].w);
          d.z = pkbf(f[2*kq+1].x, f[2*kq+1].y);
          d.w = pkbf(f[2*kq+1].z, f[2*kq+1].w);
          ntile[buf][(sr*4 + kq)*24 + sp] = d;
        }
      }
    } else {
#pragma unroll
      for (int qq = 0; qq < 2; ++qq) {
        const int q = pq0 + 2*qq;
        const float* s = prow + ks*32 + q*8;
        const float4 a0 = *(const float4*)s;
        const float4 a1 = *(const float4*)(s + 4);
        uint4 pd;
        pd.x = pkbf(a0.x, a0.y); pd.y = pkbf(a0.z, a0.w);
        pd.z = pkbf(a1.x, a1.y); pd.w = pkbf(a1.z, a1.w);
        ptile[buf][(prow_i*4 + q)*16 + ppx] = pd;
      }
    }
  };

  stage(0, 0);

#pragma unroll 1
  for (int ks = 0; ks < 4; ++ks) {
    __syncthreads();                    // buf[ks&1] ready; buf^1 free
    if (ks < 3) stage(ks + 1, (ks + 1) & 1);

    const int cur = ks & 1;
    U4S8 af;
    af.q = ptile[cur][(yr*4 + lq)*16 + lm];   // A[m=lm][k=lq*8+j]
    const uint4* nt = ntile[cur];
    if (hf == 0) cost_mma<0,5>(nt, yr, lq, lm, af.s, acc);
    else         cost_mma<5,4>(nt, yr, lq, lm, af.s, acc);
  }

  // band extraction: lane holds C[m=lq*4+reg][p=t*16+lm]; od = p - m
  const int DY0 = hf ? 5 : 0, NDY = hf ? 4 : 5;
#pragma unroll
  for (int t = 0; t < 2; ++t) {
#pragma unroll
    for (int reg = 0; reg < 4; ++reg) {
      const int m  = lq*4 + reg;
      const int od = t*16 + lm - m;
      if (od >= 0 && od <= 8) {
        __half* bp = &cost[((size_t)(b*HH + y)*WW + x0 + m)*96 + DY0*9 + od];
#pragma unroll
        for (int d = 0; d < 5; ++d) {
          if (d < NDY) {                // wave-uniform guard
            float v = acc[d][t][reg] * 0.0078125f;
            v = (v >= 0.f) ? v : 0.1f * v;
            bp[d*9] = __float2half(v);
          }
        }
      }
    }
  }
}

// -------------------------------------------------------------------------
// Kernel 2 (MFMA): conv as GEMM + gather.  (unchanged from round 4)
// G[px, j=tap*2+n] = sum_k feat[px,k] * W[tap,k,n]   (M=324, K=352, N=18->32)
// out[y,x,n] = cb[n] + sum_tap G[y+dy-1, x+dx-1, tap*2+n]
// -------------------------------------------------------------------------
__global__ __launch_bounds__(512) void k_conv_gemm(const float* __restrict__ prv,
                                                   const float* __restrict__ nxt,
                                                   const __half* __restrict__ cost,
                                                   const float* __restrict__ cw,
                                                   const float* __restrict__ cb,
                                                   float* __restrict__ out) {
  const int tw0 = blockIdx.x*16, th0 = blockIdx.y*16, b = blockIdx.z;
  const int tid = threadIdx.x;
  const int w = tid >> 6, l = tid & 63;
  const int lm = l & 15, lq = l >> 4;

  __shared__ __align__(16) char smem[49408];
  uint4*        feat16 = (uint4*)smem;               // [336 px][40 half]
  float*        Gf     = (float*)smem;               // [324][20] f32 (aliased)
  float2*       Gf2    = (float2*)smem;
  uint4*        B2     = (uint4*)(smem + 26880);     // [(kc*4+lq)*32 + j]
  __half*       B2h    = (__half*)(smem + 26880);

#pragma unroll 1
  for (int i = tid; i < 5632; i += 512) ((unsigned int*)B2)[i] = 0u;
#pragma unroll 1
  for (int i = tid; i < 240; i += 512) ((unsigned int*)smem)[6480 + i] = 0u;
#pragma unroll 1
  for (int i = tid; i < 352*18; i += 512) {
    const int ci = i / 18, j = i - 18*ci;
    if (ci >= 81 && ci < 96) continue;
    const int wci = (ci < 81) ? ci : ci - 15;
    const int tap = j >> 1, n = j & 1;
    const float v = cw[(tap*337 + wci)*2 + n];
    const int kk = ci & 31;
    B2h[((((ci >> 5)*4 + (kk >> 3))*32) + j)*8 + (kk & 7)] = __float2half(v);
  }

  f32x4 acc[3][2];
#pragma unroll
  for (int i = 0; i < 3; ++i) { acc[i][0] = (f32x4){0,0,0,0}; acc[i][1] = (f32x4){0,0,0,0}; }

#pragma unroll 1
  for (int kc = 0; kc < 11; ++kc) {
    __syncthreads();
#pragma unroll 1
    for (int i = tid; i < 648; i += 512) {
      const int px = i >> 1, half = i & 1;
      const int hr = px / 18, hc = px - 18*hr;
      const int gr = th0 - 1 + hr, gc = tw0 - 1 + hc;
      uint4 d0 = make_uint4(0,0,0,0), d1 = make_uint4(0,0,0,0);
      if ((unsigned)gr < HH && (unsigned)gc < WW) {
        const size_t pixi = (size_t)(b*HH + gr)*WW + gc;
        if (kc < 3) {
          const uint4* cs = (const uint4*)&cost[pixi*96 + kc*32 + half*16];
          d0 = cs[0]; d1 = cs[1];
        } else {
          const float* src = (kc < 7) ? prv : nxt;
          const int c0 = ((kc < 7) ? (kc-3) : (kc-7))*32 + half*16;
          const float4 f0 = *(const float4*)&src[pixi*128 + c0];
          const float4 f1 = *(const float4*)&src[pixi*128 + c0 + 4];
          const float4 f2 = *(const float4*)&src[pixi*128 + c0 + 8];
          const float4 f3 = *(const float4*)&src[pixi*128 + c0 + 12];
          d0 = make_uint4(pack2(f0.x,f0.y), pack2(f0.z,f0.w), pack2(f1.x,f1.y), pack2(f1.z,f1.w));
          d1 = make_uint4(pack2(f2.x,f2.y), pack2(f2.z,f2.w), pack2(f3.x,f3.y), pack2(f3.z,f3.w));
        }
      }
      feat16[5*px + 2*half]     = d0;
      feat16[5*px + 2*half + 1] = d1;
    }
    __syncthreads();

    U4H8 bf0, bf1;
    bf0.q = B2[(kc*4 + lq)*32 + lm];
    bf1.q = B2[(kc*4 + lq)*32 + 16 + lm];
#pragma unroll
    for (int i = 0; i < 3; ++i) {
      const int mf = w + 8*i;
      if (mf < 21) {
        U4H8 af;
        af.q = feat16[5*(16*mf + lm) + lq];
        acc[i][0] = __builtin_amdgcn_mfma_f32_16x16x32_f16(af.h, bf0.h, acc[i][0], 0, 0, 0);
        acc[i][1] = __builtin_amdgcn_mfma_f32_16x16x32_f16(af.h, bf1.h, acc[i][1], 0, 0, 0);
      }
    }
  }
  __syncthreads();

#pragma unroll
  for (int i = 0; i < 3; ++i) {
    const int mf = w + 8*i;
    if (mf >= 21) continue;
#pragma unroll
    for (int r = 0; r < 4; ++r) {
      const int px = 16*mf + lq*4 + r;
      if (px < 324) {
        Gf[px*20 + lm] = acc[i][0][r];
        if (lm < 2) Gf[px*20 + 16 + lm] = acc[i][1][r];
      }
    }
  }
  __syncthreads();

  if (tid < 512) {
    const int px = tid >> 1, n = tid & 1;
    const int ty = px >> 4, tx = px & 15;
    float s = cb[n];
#pragma unroll
    for (int p = 0; p < 9; ++p) {
      const int dy = p / 3, dx = p - 3*dy;
      const int hp = (ty + dy)*18 + (tx + dx);
      const float2 g = Gf2[hp*10 + p];
      s += n ? g.y : g.x;
    }
    out[((size_t)(b*HH + th0 + ty)*WW + (tw0 + tx))*2 + n] = s;
  }
}

extern "C" void kernel_launch(void* const* d_in, const int* in_sizes, int n_in,
                              void* d_out, int out_size, void* d_ws, size_t ws_size,
                              hipStream_t stream) {
  const float* prv = (const float*)d_in[0];
  const float* nxt = (const float*)d_in[1];
  const float* cw  = (const float*)d_in[2];
  const float* cb  = (const float*)d_in[3];
  __half* cost = (__half*)d_ws;   // 16*96*96*96*2 = 28,311,552 bytes

  k_cost_mfma<<<dim3(6, 24, 16), dim3(512), 0, stream>>>(prv, nxt, cost);
  k_conv_gemm<<<dim3(6, 6, 16), dim3(512), 0, stream>>>(prv, nxt, cost, cw, cb, (float*)d_out);
}